// Round 12
// baseline (287.454 us; speedup 1.0000x reference)
//
#include <hip/hip_runtime.h>

#define HH 384
#define WW 384
#define OUTD 370
#define NPIX (4 * OUTD * OUTD)
#define NSHIFT 99

// ---- tile geometry: 32 wide x 48 tall (R10/R11, measured conflict-free) ----
// Bank law: LDS conflicts are per 32-lane phase; (stride mod 32, unit-decode)
// must biject each half-wave onto the 32 banks. hr=u>>2, hc0=(u&3)<<3 with
// L-stride 47 (==15) and tmp-stride 55 (==23) is bijective for all access classes.
#define S2H 48
#define LS2 47           // L stride
#define LR2 63           // L rows = 48 + 6 conv + 9 shift span
#define TM2 55           // tmp_T stride = 54 rows + 1
#define NXT2 12          // ceil(370/32)
#define NYT2 8           // ceil(370/48)
#define TTS2 (32 * TM2)
#define TILE 32
#define GRID_BLKS (NXT2 * NYT2 * 4 * 2)   // 768 = exactly 3 blocks/CU on 256 CUs
#define CNT_OFF ((size_t)4 * NPIX * sizeof(float))  // barrier counter after V/M planes

#define G0 0.32465246735834974f   // exp(-9/8)
#define G1 0.6065306597126334f    // exp(-4/8)
#define G2 0.8824969025845955f    // exp(-1/8)
#define KS 0.039788735772973836f  // 1/(8*pi)
#define LOG2E 1.4426950408889634f

__device__ __forceinline__ float tap7(const float* v)
{
    return fmaf(G0, v[0] + v[6],
           fmaf(G1, v[1] + v[5],
           fmaf(G2, v[2] + v[4], v[3])));
}

__device__ __forceinline__ void shift_of(int s, int& sx, int& sy)
{
    int t = (s < 55) ? s : s + 1;    // skip (0,0)
    sx = t / 10 - 5;
    sy = t - (t / 10) * 10 - 5;
}

template<int W, int Hrows>
__device__ __forceinline__ void load_tile(const float* __restrict__ img,
                                          int oy0, int ox0, float* L, int tid)
{
    for (int i = tid; i < W * Hrows; i += 256) {
        int r = i / W, c = i - r * W;
        int gr = oy0 + r; if (gr >= HH) gr -= HH;
        int gc = ox0 + c; if (gc >= WW) gc -= WW;
        L[i] = img[gr * WW + gc];
    }
}

// horizontal 7-tap over inline diff^2; 8 outputs -> transposed tmp (stride TS)
template<int LW, int TS>
__device__ __forceinline__ void horiz8(const float* __restrict__ Lb,
                                       const float* __restrict__ cA,
                                       float* __restrict__ tb,
                                       int r, int c0, int sx, int sy)
{
    const float* Ls = &Lb[(r + 4 - sy) * LW + (c0 + 4 - sx)];
    float v[14];
#pragma unroll
    for (int t = 0; t < 14; ++t) { float d = cA[t] - Ls[t]; v[t] = d * d; }
    float* o = &tb[c0 * TS + r];
#pragma unroll
    for (int k = 0; k < 8; ++k) o[k * TS] = tap7(v + k);
}

// device-scope counting barrier; safe because grid == residency (768 = 3/CU exact,
// LDS 50.7KB -> 3 fit, VGPR 68 << 170). Release/acquire via __threadfence (the
// cooperative-groups grid.sync pattern).
__device__ __forceinline__ void grid_barrier(unsigned* cnt, int tid)
{
    __syncthreads();
    if (tid == 0) {
        __threadfence();                          // release: V/M stores visible device-wide
        atomicAdd(cnt, 1u);
        while (atomicAdd(cnt, 0u) < (unsigned)GRID_BLKS)
            __builtin_amdgcn_s_sleep(8);
        __threadfence();                          // acquire
    }
    __syncthreads();
}

// Fused MIND loss: phase 1 = stage2 (z = image), grid barrier, phase 2 = stage3
// (z = shift half). Grids identical (96 tiles x 4 batch x 2).
extern "C" __global__ void __launch_bounds__(256, 3)
mind_fused(const float* __restrict__ pred, const float* __restrict__ gt,
           float* __restrict__ ws, unsigned* __restrict__ cnt,
           float* __restrict__ out)
{
    __shared__ float LP[LR2 * LS2];
    __shared__ float LG[LR2 * LS2];
    __shared__ float tTA[2][TTS2];
    __shared__ float tTB[2][TTS2];
    __shared__ float wred[4];
    const int tid = threadIdx.x;
    const int b = blockIdx.y, z = blockIdx.z;
    const int oy0 = ((int)blockIdx.x / NXT2) * S2H;
    const int ox0 = ((int)blockIdx.x % NXT2) * TILE;

    const int hr = tid >> 2, hc0 = (tid & 3) << 3;
    const int vx = tid & 31, vy0 = (tid >> 5) * 6;

    // ======== phase 1: stage2 for image z (R11 structure, measured 104us) ========
    {
        float* L = LP;                     // reuse phase-2 buffers
        float (*tT)[TTS2] = tTA;
        const float* img = (z ? gt : pred) + (size_t)b * HH * WW;
        load_tile<LS2, LR2>(img, oy0, ox0, L, tid);
        if (blockIdx.x == 0 && b == 0 && z == 0 && tid == 0) out[0] = 0.f;
        const bool hasH = tid < 216;
        __syncthreads();

        float cA[14];
        if (hasH) {
            const float* p = &L[(hr + 4) * LS2 + hc0 + 4];
#pragma unroll
            for (int t = 0; t < 14; ++t) cA[t] = p[t];
        }

        float dmin[6], vsum[6];
#pragma unroll
        for (int k = 0; k < 6; ++k) { dmin[k] = 1e30f; vsum[k] = 0.f; }

        for (int s = 0; s < NSHIFT; ++s) {
            int sx, sy; shift_of(s, sx, sy);
            if (hasH) horiz8<LS2, TM2>(L, cA, tT[s & 1], hr, hc0, sx, sy);
            __syncthreads();   // tT[s&1] ready; buffer alternation -> WAR safe
            {
                const float* t = &tT[s & 1][vx * TM2 + vy0];
                float w[12];
#pragma unroll
                for (int j = 0; j < 12; ++j) w[j] = t[j];
                const bool card = (sx * sx + sy * sy) == 1;
#pragma unroll
                for (int k = 0; k < 6; ++k) {
                    float D = KS * tap7(w + k);
                    dmin[k] = fminf(dmin[k], D);
                    if (card) vsum[k] += D;
                }
            }
        }

        {
            float* V = ws + (size_t)z * NPIX;
            float* M = ws + (size_t)(2 + z) * NPIX;
            const int ox = ox0 + vx;
#pragma unroll
            for (int k = 0; k < 6; ++k) {
                int oy = oy0 + vy0 + k;
                if (oy < OUTD && ox < OUTD) {
                    size_t idx = ((size_t)b * OUTD + oy) * OUTD + ox;
                    V[idx] = vsum[k] * 0.25f + 1e-5f;
                    M[idx] = dmin[k];
                }
            }
        }
    }

    // ======== grid barrier: all 768 blocks (co-resident by construction) ========
    grid_barrier(cnt, tid);

    // ======== phase 2: stage3 for shift-half z (R11 structure, measured 104us) ========
    {
        const int zh = z;
        load_tile<LS2, LR2>(pred + (size_t)b * HH * WW, oy0, ox0, LP, tid);
        load_tile<LS2, LR2>(gt   + (size_t)b * HH * WW, oy0, ox0, LG, tid);

        // pass A: units 0..255 = P:0..215, G:0..39; pass B: tid<176 -> G units 40..215
        const bool gA = tid >= 216;
        const int uA = gA ? tid - 216 : tid;
        const int rA = uA >> 2, cA0 = (uA & 3) << 3;
        const float* LbA = gA ? LG : LP;
        const bool hasB = tid < 176;
        const int uB = tid + 40;
        const int rB = uB >> 2, cB0 = (uB & 3) << 3;

        const float* Vp = ws;
        const float* Vg = ws + (size_t)NPIX;
        const float* Mp = ws + (size_t)2 * NPIX;
        const float* Mg = ws + (size_t)3 * NPIX;
        float rvp[6], rvg[6], mp[6], mg[6];
        bool valid[6];
#pragma unroll
        for (int k = 0; k < 6; ++k) {
            int oy = oy0 + vy0 + k, ox = ox0 + vx;
            valid[k] = (oy < OUTD) && (ox < OUTD);
            if (valid[k]) {
                size_t idx = ((size_t)b * OUTD + oy) * OUTD + ox;
                rvp[k] = LOG2E / Vp[idx]; mp[k] = Mp[idx];
                rvg[k] = LOG2E / Vg[idx]; mg[k] = Mg[idx];
            } else {
                rvp[k] = 0.f; mp[k] = 0.f; rvg[k] = 0.f; mg[k] = 0.f;
            }
        }
        __syncthreads();

        float cWA[14], cWB[14];
        {
            const float* p = &LbA[(rA + 4) * LS2 + cA0 + 4];
#pragma unroll
            for (int t = 0; t < 14; ++t) cWA[t] = p[t];
        }
        if (hasB) {
            const float* p = &LG[(rB + 4) * LS2 + cB0 + 4];
#pragma unroll
            for (int t = 0; t < 14; ++t) cWB[t] = p[t];
        }

        const int s_beg = zh * 50;
        const int s_end = zh ? NSHIFT : 50;
        float acc = 0.f;

        for (int s = s_beg; s < s_end; ++s) {
            const int buf = s & 1;
            int sx, sy; shift_of(s, sx, sy);
            horiz8<LS2, TM2>(LbA, cWA, (gA ? tTB[buf] : tTA[buf]), rA, cA0, sx, sy);
            if (hasB) horiz8<LS2, TM2>(LG, cWB, tTB[buf], rB, cB0, sx, sy);
            __syncthreads();              // buffers ready; WAR safe by alternation
            float Dp[6], Dg[6];
            {
                const float* t = &tTA[buf][vx * TM2 + vy0];
                float w[12];
#pragma unroll
                for (int j = 0; j < 12; ++j) w[j] = t[j];
#pragma unroll
                for (int k = 0; k < 6; ++k) Dp[k] = KS * tap7(w + k);
            }
            {
                const float* t = &tTB[buf][vx * TM2 + vy0];
                float w[12];
#pragma unroll
                for (int j = 0; j < 12; ++j) w[j] = t[j];
#pragma unroll
                for (int k = 0; k < 6; ++k) Dg[k] = KS * tap7(w + k);
            }
#pragma unroll
            for (int k = 0; k < 6; ++k) {
                if (valid[k]) {
                    float ep = exp2f((mp[k] - Dp[k]) * rvp[k]);
                    float eg = exp2f((mg[k] - Dg[k]) * rvg[k]);
                    acc += fabsf(ep - eg);
                }
            }
        }

#pragma unroll
        for (int off = 32; off > 0; off >>= 1) acc += __shfl_down(acc, off, 64);
        const int lane = tid & 63, wv = tid >> 6;
        if (lane == 0) wred[wv] = acc;
        __syncthreads();
        if (tid == 0) {
            const float SC = (float)(1.0 / 54212400.0);  // 1/(4*370*370*99)
            atomicAdd(out, (wred[0] + wred[1] + wred[2] + wred[3]) * SC);
        }
    }
}

extern "C" void kernel_launch(void* const* d_in, const int* in_sizes, int n_in,
                              void* d_out, int out_size, void* d_ws, size_t ws_size,
                              hipStream_t stream)
{
    (void)in_sizes; (void)n_in; (void)out_size; (void)ws_size;
    const float* pred = (const float*)d_in[0];
    const float* gt   = (const float*)d_in[1];
    float* out = (float*)d_out;
    float* ws  = (float*)d_ws;
    unsigned* cnt = (unsigned*)((char*)d_ws + CNT_OFF);

    hipMemsetAsync(cnt, 0, 64, stream);   // barrier counter only; d_out zeroed in-kernel

    dim3 g(NXT2 * NYT2, 4, 2);            // 768 blocks = 3/CU exact (co-resident)
    mind_fused<<<g, 256, 0, stream>>>(pred, gt, ws, cnt, out);
}

// Round 13
// 226.609 us; speedup vs baseline: 1.2685x; 1.2685x over previous
//
#include <hip/hip_runtime.h>

#define HH 384
#define WW 384
#define OUTD 370
#define NSHIFT 99

// ---- fused per-tile geometry: 32 wide x 24 tall ----
// 192 tiles x 4 batch = 768 blocks = exactly 3/CU. Dependency stage2->stage3 is
// per-tile, so fusion needs NO grid barrier (R12 lesson: grid barrier costs ~47us).
// Bank law (R5..R12): LDS conflicts are per 32-lane phase; (stride mod 32, decode)
// must biject each half-wave onto banks. L-stride 47 (==15), tmp-stride 31 (==-1),
// decode r=u>>2, c0=(u&3)<<3, vert -vx: all proven <=2-way (free).
#define TW 32
#define TH 24
#define LSTR 47          // L stride
#define LROWS 39         // 24 + 6 conv + 9 shift span
#define LPADSZ 1856      // 39*47=1833 padded to 32-multiple -> LG base bank-aligned
#define TMS 31           // tmp_T stride (30 rows + 1)
#define TMROWS 30
#define TTSZ (TW * TMS)  // 992 floats (32-multiple)
#define NXT 12           // ceil(370/32)
#define NYT 16           // ceil(370/24)

#define G0 0.32465246735834974f   // exp(-9/8)
#define G1 0.6065306597126334f    // exp(-4/8)
#define G2 0.8824969025845955f    // exp(-1/8)
#define KS 0.039788735772973836f  // 1/(8*pi)
#define LOG2E 1.4426950408889634f

__device__ __forceinline__ float tap7(const float* v)
{
    return fmaf(G0, v[0] + v[6],
           fmaf(G1, v[1] + v[5],
           fmaf(G2, v[2] + v[4], v[3])));
}

__device__ __forceinline__ void shift_of(int s, int& sx, int& sy)
{
    int t = (s < 55) ? s : s + 1;    // skip (0,0)
    sx = t / 10 - 5;
    sy = t - (t / 10) * 10 - 5;
}

__device__ __forceinline__ void load_tile(const float* __restrict__ img,
                                          int oy0, int ox0, float* L, int tid)
{
    for (int i = tid; i < LROWS * LSTR; i += 256) {
        int r = i / LSTR, c = i - r * LSTR;
        int gr = oy0 + r; if (gr >= HH) gr -= HH;   // circular wrap
        int gc = ox0 + c; if (gc >= WW) gc -= WW;
        L[i] = img[gr * WW + gc];
    }
}

// horizontal 7-tap over inline diff^2; 8 outputs -> transposed tmp
__device__ __forceinline__ void horiz8(const float* __restrict__ Lb,
                                       const float* __restrict__ cA,
                                       float* __restrict__ tb,
                                       int r, int c0, int sx, int sy)
{
    const float* Ls = &Lb[(r + 4 - sy) * LSTR + (c0 + 4 - sx)];
    float v[14];
#pragma unroll
    for (int t = 0; t < 14; ++t) { float d = cA[t] - Ls[t]; v[t] = d * d; }
    float* o = &tb[c0 * TMS + r];
#pragma unroll
    for (int k = 0; k < 8; ++k) o[k * TMS] = tap7(v + k);
}

// vertical 7-tap, 3 outputs from 9 consecutive tmp_T values
__device__ __forceinline__ void vert3(const float* __restrict__ tT, int vx, int vy0, float* D)
{
    const float* t = &tT[vx * TMS + vy0];
    float w[9];
#pragma unroll
    for (int j = 0; j < 9; ++j) w[j] = t[j];
#pragma unroll
    for (int k = 0; k < 3; ++k) D[k] = KS * tap7(w + k);
}

// Fused per-tile MIND loss: phase 1 computes V,minD (both images) into registers;
// phase 2 recomputes D and accumulates |exp2 - exp2|. No ws, no grid barrier.
extern "C" __global__ void __launch_bounds__(256, 3)
mind_fused(const float* __restrict__ pred, const float* __restrict__ gt,
           float* __restrict__ out)
{
    __shared__ float LP[LPADSZ];
    __shared__ float LG[LPADSZ];
    __shared__ float tTP[2][TTSZ];
    __shared__ float tTG[2][TTSZ];
    __shared__ float wred[4];
    const int tid = threadIdx.x;
    const int b = blockIdx.y;
    const int oy0 = ((int)blockIdx.x / NXT) * TH;
    const int ox0 = ((int)blockIdx.x % NXT) * TW;

    load_tile(pred + (size_t)b * HH * WW, oy0, ox0, LP, tid);
    load_tile(gt   + (size_t)b * HH * WW, oy0, ox0, LG, tid);

    // horiz: 240 units = 2 images x 30 rows x 4 col-octets; single pass, 94% active
    const bool hasH = tid < 240;
    const bool hG = tid >= 120;
    const int hu = hG ? tid - 120 : tid;
    const int hr = hu >> 2, hc0 = (hu & 3) << 3;
    const float* Lh = hG ? LG : LP;
    float* const tb0 = hG ? tTG[0] : tTP[0];
    float* const tb1 = hG ? tTG[1] : tTP[1];

    // vert: 256 units = 32 cols x 8 strips of 3 rows, both images per thread
    const int vx = tid & 31, vy0 = (tid >> 5) * 3;

    __syncthreads();

    float cA[14];
    if (hasH) {
        const float* p = &Lh[(hr + 4) * LSTR + hc0 + 4];
#pragma unroll
        for (int t = 0; t < 14; ++t) cA[t] = p[t];
    }

    // ---- phase 1: V (4 cardinals) and minD over 99 shifts, both images ----
    float dmp[3], vsp[3], dmg[3], vsg[3];
#pragma unroll
    for (int k = 0; k < 3; ++k) { dmp[k] = 1e30f; vsp[k] = 0.f; dmg[k] = 1e30f; vsg[k] = 0.f; }

    for (int s = 0; s < NSHIFT; ++s) {
        int sx, sy; shift_of(s, sx, sy);
        if (hasH) horiz8(Lh, cA, (s & 1) ? tb1 : tb0, hr, hc0, sx, sy);
        __syncthreads();   // tT[s&1] ready; alternation -> WAR with vert(s-1) safe
        float Dp[3], Dg[3];
        vert3(tTP[s & 1], vx, vy0, Dp);
        vert3(tTG[s & 1], vx, vy0, Dg);
        const bool card = (sx * sx + sy * sy) == 1;
#pragma unroll
        for (int k = 0; k < 3; ++k) {
            dmp[k] = fminf(dmp[k], Dp[k]);
            dmg[k] = fminf(dmg[k], Dg[k]);
            if (card) { vsp[k] += Dp[k]; vsg[k] += Dg[k]; }
        }
    }

    // loss constants from registers (no global round-trip)
    float rvp[3], rvg[3];
    bool valid[3];
#pragma unroll
    for (int k = 0; k < 3; ++k) {
        int oy = oy0 + vy0 + k, ox = ox0 + vx;
        valid[k] = (oy < OUTD) && (ox < OUTD);
        rvp[k] = LOG2E / (vsp[k] * 0.25f + 1e-5f);
        rvg[k] = LOG2E / (vsg[k] * 0.25f + 1e-5f);
    }

    __syncthreads();   // phase boundary: protect buf reuse (phase2 s=0 writes buf 0)

    // ---- phase 2: recompute D, accumulate |exp2((m-D)*rv)p - (...)g| ----
    float acc = 0.f;
    for (int s = 0; s < NSHIFT; ++s) {
        int sx, sy; shift_of(s, sx, sy);
        if (hasH) horiz8(Lh, cA, (s & 1) ? tb1 : tb0, hr, hc0, sx, sy);
        __syncthreads();
        float Dp[3], Dg[3];
        vert3(tTP[s & 1], vx, vy0, Dp);
        vert3(tTG[s & 1], vx, vy0, Dg);
#pragma unroll
        for (int k = 0; k < 3; ++k) {
            if (valid[k]) {
                float ep = exp2f((dmp[k] - Dp[k]) * rvp[k]);
                float eg = exp2f((dmg[k] - Dg[k]) * rvg[k]);
                acc += fabsf(ep - eg);
            }
        }
    }

#pragma unroll
    for (int off = 32; off > 0; off >>= 1) acc += __shfl_down(acc, off, 64);
    const int lane = tid & 63, wv = tid >> 6;
    if (lane == 0) wred[wv] = acc;
    __syncthreads();
    if (tid == 0) {
        const float SC = (float)(1.0 / 54212400.0);  // 1/(4*370*370*99)
        atomicAdd(out, (wred[0] + wred[1] + wred[2] + wred[3]) * SC);
    }
}

extern "C" void kernel_launch(void* const* d_in, const int* in_sizes, int n_in,
                              void* d_out, int out_size, void* d_ws, size_t ws_size,
                              hipStream_t stream)
{
    (void)in_sizes; (void)n_in; (void)out_size; (void)d_ws; (void)ws_size;
    const float* pred = (const float*)d_in[0];
    const float* gt   = (const float*)d_in[1];
    float* out = (float*)d_out;

    hipMemsetAsync(d_out, 0, sizeof(float), stream);

    dim3 g(NXT * NYT, 4, 1);   // 192 tiles x 4 batch = 768 blocks = 3/CU exact
    mind_fused<<<g, 256, 0, stream>>>(pred, gt, out);
}